// Round 12
// baseline (80.063 us; speedup 1.0000x reference)
//
#include <hip/hip_runtime.h>
#include <hip/hip_bf16.h>

#define IN_CH   128
#define HIDDEN  256
#define H2DIM   128
#define KS1     17             // GEMM1 k-steps total (K=544); pass A: 0..7, pass B: 8..16
#define KS2     8              // GEMM2 k-steps (K=256)
#define NT1     16
#define NT2     8
#define FSTR    296            // feats LDS k-stride (ushort) for the half buffer
#define H1S     264            // h1 overlay stride (ushort)
#define CAP     64             // adjacency-list cap (fallbacks if deg>CAP)
#define T1PACK  (NT1*KS1*64)   // 17408
#define T2PACK  (NT2*KS2*64)   // 4096

typedef short short8v __attribute__((ext_vector_type(8)));
typedef float f32x4   __attribute__((ext_vector_type(4)));

__device__ __forceinline__ ushort f2bf(float f) {
  union { float f; uint32_t u; } c; c.f = f;
  uint32_t u = c.u + 0x7FFFu + ((c.u >> 16) & 1u);   // RNE
  return (ushort)(u >> 16);
}
__device__ __forceinline__ float bf2f(ushort h) {
  union { uint32_t u; float f; } c; c.u = ((uint32_t)h) << 16;
  return c.f;
}
__device__ __forceinline__ float bfLo(uint32_t u) { return bf2f((ushort)(u & 0xffffu)); }
__device__ __forceinline__ float bfHi(uint32_t u) { return bf2f((ushort)(u >> 16)); }
__device__ __forceinline__ uint32_t pk2(float a, float b) {
  __hip_bfloat162 h = __float22bfloat162_rn(make_float2(a, b));
  union { __hip_bfloat162 h; uint32_t u; } c; c.h = h;
  return c.u;
}

// ---------------- kernel 1: zero bitset + pack W1(K-folded)/W2 ----------------
__global__ void k_prep(const float* __restrict__ W1, const float* __restrict__ W2,
                       ushort* __restrict__ w1p, ushort* __restrict__ w2p,
                       uint32_t* __restrict__ bits, int nwords) {
  int t = blockIdx.x * blockDim.x + threadIdx.x;
  if (t < T1PACK) {
    int l = t & 63;
    int rest = t >> 6;
    int ks = rest % KS1;
    int nt = rest / KS1;
    int n  = nt * 16 + (l & 15);
    int k0 = ks * 32 + (l >> 4) * 8;
    short8v v;
    #pragma unroll
    for (int j = 0; j < 8; ++j) {
      int k = k0 + j;
      float val;
      if (k < 128)      val = W1[(size_t)k * HIDDEN + n] + W1[(size_t)(512 + k) * HIDDEN + n];
      else if (k < 256) val = W1[(size_t)k * HIDDEN + n] + W1[(size_t)(384 + k) * HIDDEN + n];
      else if (k < 512) val = W1[(size_t)k * HIDDEN + n];
      else if (k < 516) val = W1[(size_t)(k + 128) * HIDDEN + n];   // rows 640..643
      else              val = 0.f;
      v[j] = (short)f2bf(val);
    }
    *(short8v*)(w1p + (size_t)t * 8) = v;
  } else if (t < T1PACK + T2PACK) {
    int t2 = t - T1PACK;
    int l = t2 & 63;
    int rest = t2 >> 6;
    int ks = rest % KS2;
    int nt = rest / KS2;
    int n  = nt * 16 + (l & 15);
    int k0 = ks * 32 + (l >> 4) * 8;
    short8v v;
    #pragma unroll
    for (int j = 0; j < 8; ++j)
      v[j] = (short)f2bf(W2[(size_t)(k0 + j) * H2DIM + n]);
    *(short8v*)(w2p + (size_t)t2 * 8) = v;
  }
  int stride = gridDim.x * blockDim.x;
  for (int i = t; i < nwords; i += stride) bits[i] = 0u;
}

// ---------------- kernel 2: build adjacency bitset ----------------
__global__ void k_build_adj(const int* __restrict__ ei, int E, int roww,
                            uint32_t* __restrict__ bits) {
  int e = blockIdx.x * blockDim.x + threadIdx.x;
  if (e >= E) return;
  int u = ei[e];
  int v = ei[E + e];
  if (u == v) return;
  atomicOr((unsigned int*)&bits[(size_t)u * roww + (v >> 5)], 1u << (v & 31));
}

// -- kernel 3: node stats (packed float2) + sorted adjacency lists + bf16 x --
__global__ void k_node_lists(const uint32_t* __restrict__ bits, const float* __restrict__ x,
                             int nnodes, int roww,
                             float2* __restrict__ dn, float2* __restrict__ nodeinv,
                             ushort* __restrict__ adjl, ushort* __restrict__ xbf) {
  int node = blockIdx.x * (blockDim.x >> 6) + (threadIdx.x >> 6);
  int lane = threadIdx.x & 63;
  if (node >= nnodes) return;
  const uint32_t* row = bits + (size_t)node * roww;
  uint32_t wd[4];
  int c = 0;
  #pragma unroll
  for (int j = 0; j < 4; ++j) { wd[j] = row[lane * 4 + j]; c += __popc(wd[j]); }
  int sum = c;
  #pragma unroll
  for (int off = 1; off < 64; off <<= 1) {
    int t = __shfl_up(sum, off);
    if (lane >= off) sum += t;
  }
  int excl = sum - c;
  int total = __shfl(sum, 63);
  ushort* lst = adjl + (size_t)node * CAP;
  int pos = excl;
  #pragma unroll
  for (int j = 0; j < 4; ++j) {
    uint32_t m = wd[j];
    int base = (lane * 4 + j) * 32;
    while (m) {
      int b = __ffs(m) - 1;
      if (pos < CAP) lst[pos] = (ushort)(base + b);
      ++pos;
      m &= m - 1;
    }
  }
  float2 xa = *(const float2*)(x + (size_t)node * IN_CH + 2 * lane);
  *(uint32_t*)(xbf + (size_t)node * IN_CH + 2 * lane) = pk2(xa.x, xa.y);
  float ss = xa.x * xa.x + xa.y * xa.y;
  #pragma unroll
  for (int off = 32; off; off >>= 1) ss += __shfl_xor(ss, off);
  if (lane == 0) {
    float d = (float)total;
    dn[node] = make_float2(d, sqrtf(ss));
    float il = (total > 1) ? 1.0f / logf(d) : 0.0f;
    float ig = (total > 0) ? 1.0f / d : 0.0f;
    nodeinv[node] = make_float2(il, ig);
  }
}

// ---------------- kernel 4: fused features + pair stats + MFMA MLP ----------
// 64 pairs/block, 512 threads (8 waves). Pair stats via register-resident
// sorted-list intersection (6-step shfl binary search) — no bitset probe in
// the hot path. bf16 x gathers. 2-pass GEMM1 over half-width feats buffer.
__global__ __launch_bounds__(512, 4) void k_mlp11(
    const ushort* __restrict__ xbf, const int* __restrict__ pairs,
    const uint32_t* __restrict__ bits, int roww,
    const float2* __restrict__ dn, const float2* __restrict__ nodeinv,
    const ushort* __restrict__ adjl,
    const ushort* __restrict__ w1p, const float* __restrict__ b1,
    const ushort* __restrict__ w2p, const float* __restrict__ b2,
    const float* __restrict__ W3, const float* __restrict__ b3,
    float* __restrict__ out, int P)
{
  __shared__ ushort feats[64 * FSTR];   // 37,888 B; h1 (stride 264) overlays later
  __shared__ float outacc[64];
  __shared__ int us[64], vs[64];

  int tid = threadIdx.x;
  int pb = blockIdx.x * 64;
  int w  = tid >> 6, l = tid & 63;
  int pg = l >> 3, g = l & 7;        // feature build: 8 lanes per pair
  int lr = l & 15;                   // MFMA A row / B,C col within tile
  int lk = l >> 4;                   // MFMA k-group / C row group

  if (tid < 64) {
    int2 pr = ((const int2*)pairs)[pb + tid];
    us[tid] = pr.x; vs[tid] = pr.y;
    outacc[tid] = b3[0];
  }
  __syncthreads();

  int p = w * 8 + pg;
  int u = us[p], v = vs[p];
  ushort* fpR = feats + p * FSTR;
  ushort* fp  = fpR + g * 16;

  // ---- pass A build: bf16 xu -> cols [0,128), xv -> [128,256); cos; pad ----
  {
    const ushort* xup = xbf + (size_t)u * IN_CH + g * 16;
    const ushort* xvp = xbf + (size_t)v * IN_CH + g * 16;
    uint4 A0 = *(const uint4*)(xup);
    uint4 A1 = *(const uint4*)(xup + 8);
    uint4 B0 = *(const uint4*)(xvp);
    uint4 B1 = *(const uint4*)(xvp + 8);
    *(uint4*)(fp)       = A0;
    *(uint4*)(fp + 8)   = A1;
    *(uint4*)(fp + 128) = B0;
    *(uint4*)(fp + 136) = B1;
    float suv = bfLo(A0.x)*bfLo(B0.x) + bfHi(A0.x)*bfHi(B0.x)
              + bfLo(A0.y)*bfLo(B0.y) + bfHi(A0.y)*bfHi(B0.y)
              + bfLo(A0.z)*bfLo(B0.z) + bfHi(A0.z)*bfHi(B0.z)
              + bfLo(A0.w)*bfLo(B0.w) + bfHi(A0.w)*bfHi(B0.w)
              + bfLo(A1.x)*bfLo(B1.x) + bfHi(A1.x)*bfHi(B1.x)
              + bfLo(A1.y)*bfLo(B1.y) + bfHi(A1.y)*bfHi(B1.y)
              + bfLo(A1.z)*bfLo(B1.z) + bfHi(A1.z)*bfHi(B1.z)
              + bfLo(A1.w)*bfLo(B1.w) + bfHi(A1.w)*bfHi(B1.w);
    suv += __shfl_xor(suv, 1);
    suv += __shfl_xor(suv, 2);
    suv += __shfl_xor(suv, 4);
    if (g == 0) {
      float nu = dn[u].y, nv = dn[v].y;
      fpR[256] = f2bf(suv / fmaxf(nu * nv, 1e-8f));
    }
    if (g < 7) *(uint2*)(fpR + 260 + 4 * g) = make_uint2(0u, 0u);
  }

  // ---- pair stats: sorted-list intersection, both lists lane-resident ----
  for (int pp = 0; pp < 8; ++pp) {
    int ps_ = w * 8 + pp;
    int uu = us[ps_], vv = vs[ps_];
    int du = (int)dn[uu].x, dv = (int)dn[vv].x;
    bool ule = du <= dv;
    int sn = ule ? uu : vv, on = ule ? vv : uu;
    int ds = ule ? du : dv, dl = ule ? dv : du;
    float cnv, aa = 0.f, ra = 0.f;
    if (dl <= CAP) {
      // primary: intersect sorted lists in registers
      int a = adjl[(size_t)sn * CAP + l];
      int b = adjl[(size_t)on * CAP + l];
      int pos = 0;                      // lower_bound of a in b[0..dl)
      #pragma unroll
      for (int st = 32; st; st >>= 1) {
        int cand = pos + st;
        int bv = __shfl(b, cand - 1);
        if (cand <= dl && bv < a) pos = cand;
      }
      int bp = __shfl(b, pos);
      bool hit = (l < ds) && (pos < dl) && (bp == a);
      unsigned long long mask = __ballot(hit);
      cnv = (float)__popcll(mask);
      if (mask) {
        float il = 0.f, ig = 0.f;
        if (hit) { float2 nv = nodeinv[a]; il = nv.x; ig = nv.y; }
        while (mask) {
          int ln = __ffsll(mask) - 1;
          aa += __shfl(il, ln);
          ra += __shfl(ig, ln);
          mask &= mask - 1;
        }
      }
    } else if (ds <= CAP) {
      // rare: longer list exceeds CAP -> probe shorter list against bitset
      bool hit = false; int nb = 0;
      if (l < ds) {
        nb = adjl[(size_t)sn * CAP + l];
        hit = (bits[(size_t)on * roww + (nb >> 5)] >> (nb & 31)) & 1u;
      }
      unsigned long long mask = __ballot(hit);
      cnv = (float)__popcll(mask);
      if (mask) {
        float il = 0.f, ig = 0.f;
        if (hit) { float2 nv = nodeinv[nb]; il = nv.x; ig = nv.y; }
        while (mask) {
          int ln = __ffsll(mask) - 1;
          aa += __shfl(il, ln);
          ra += __shfl(ig, ln);
          mask &= mask - 1;
        }
      }
    } else {
      // ~never: both lists exceed CAP -> full bitset AND
      float cnL = 0.f, aaL = 0.f, raL = 0.f;
      const uint32_t* ru = bits + (size_t)uu * roww;
      const uint32_t* rv = bits + (size_t)vv * roww;
      for (int wd = l; wd < roww; wd += 64) {
        uint32_t c = ru[wd] & rv[wd];
        cnL += (float)__popc(c);
        while (c) {
          int bb = __ffs(c) - 1;
          int idx = wd * 32 + bb;
          float2 nv = nodeinv[idx];
          aaL += nv.x; raL += nv.y;
          c &= c - 1;
        }
      }
      #pragma unroll
      for (int off = 32; off; off >>= 1) {
        cnL += __shfl_xor(cnL, off);
        aaL += __shfl_xor(aaL, off);
        raL += __shfl_xor(raL, off);
      }
      cnv = cnL; aa = aaL; ra = raL;
    }
    if (l == 0) {
      ushort* fq = feats + ps_ * FSTR;
      fq[257] = f2bf(cnv); fq[258] = f2bf(aa); fq[259] = f2bf(ra);
    }
  }
  __syncthreads();

  // ---- GEMM1 accumulators persist across both k-passes ----
  f32x4 acc[4][2];
  #pragma unroll
  for (int m = 0; m < 4; ++m)
    #pragma unroll
    for (int i = 0; i < 2; ++i) acc[m][i] = (f32x4){0.f, 0.f, 0.f, 0.f};

  const ushort* aB = feats + lr * FSTR + lk * 8;
  const ushort* bW = w1p + (size_t)(w * 2) * KS1 * 512 + l * 8;

  // ---- GEMM1 pass A: ks 0..7 (k 0..255) ----
  {
    short8v bf[2][2];
    #pragma unroll
    for (int i = 0; i < 2; ++i)
      bf[0][i] = *(const short8v*)(bW + (size_t)(i * KS1) * 512);
    #pragma unroll
    for (int ks = 0; ks < 8; ++ks) {
      int cur = ks & 1, nxt = cur ^ 1;
      if (ks + 1 < 8) {
        #pragma unroll
        for (int i = 0; i < 2; ++i)
          bf[nxt][i] = *(const short8v*)(bW + (size_t)(i * KS1 + ks + 1) * 512);
      }
      short8v am[4];
      #pragma unroll
      for (int m = 0; m < 4; ++m)
        am[m] = *(const short8v*)(aB + m * 16 * FSTR + ks * 32);
      #pragma unroll
      for (int i = 0; i < 2; ++i)
        #pragma unroll
        for (int m = 0; m < 4; ++m)
          acc[m][i] = __builtin_amdgcn_mfma_f32_16x16x32_bf16(am[m], bf[cur][i], acc[m][i], 0, 0, 0);
    }
  }
  __syncthreads();   // all waves done reading pass-A cols

  // ---- pass B build: read bf16 xu/xv back from LDS; prod -> [0,128),
  //      absdiff -> [128,256). Same-thread same-cells: no cross-thread hazard.
  {
    uint4 A0 = *(uint4*)(fp);
    uint4 A1 = *(uint4*)(fp + 8);
    uint4 B0 = *(uint4*)(fp + 128);
    uint4 B1 = *(uint4*)(fp + 136);
    uint4 P0, P1, D0, D1;
    #define PD(Au, Bu, Pu, Du)                                                 \
      {                                                                        \
        float alo = bfLo(Au), ahi = bfHi(Au);                                  \
        float blo = bfLo(Bu), bhi = bfHi(Bu);                                  \
        Pu = pk2(alo * blo, ahi * bhi);                                        \
        Du = pk2(fabsf(alo - blo), fabsf(ahi - bhi));                          \
      }
    PD(A0.x, B0.x, P0.x, D0.x) PD(A0.y, B0.y, P0.y, D0.y)
    PD(A0.z, B0.z, P0.z, D0.z) PD(A0.w, B0.w, P0.w, D0.w)
    PD(A1.x, B1.x, P1.x, D1.x) PD(A1.y, B1.y, P1.y, D1.y)
    PD(A1.z, B1.z, P1.z, D1.z) PD(A1.w, B1.w, P1.w, D1.w)
    #undef PD
    *(uint4*)(fp)       = P0;
    *(uint4*)(fp + 8)   = P1;
    *(uint4*)(fp + 128) = D0;
    *(uint4*)(fp + 136) = D1;
  }
  __syncthreads();

  // ---- GEMM1 pass B: ks 8..16 (k 256..543; buffer col = (ks-8)*32) ----
  {
    short8v bf[2][2];
    #pragma unroll
    for (int i = 0; i < 2; ++i)
      bf[0][i] = *(const short8v*)(bW + (size_t)(i * KS1 + 8) * 512);
    #pragma unroll
    for (int ks = 8; ks < KS1; ++ks) {
      int cur = ks & 1, nxt = cur ^ 1;
      if (ks + 1 < KS1) {
        #pragma unroll
        for (int i = 0; i < 2; ++i)
          bf[nxt][i] = *(const short8v*)(bW + (size_t)(i * KS1 + ks + 1) * 512);
      }
      short8v am[4];
      #pragma unroll
      for (int m = 0; m < 4; ++m)
        am[m] = *(const short8v*)(aB + m * 16 * FSTR + (ks - 8) * 32);
      #pragma unroll
      for (int i = 0; i < 2; ++i)
        #pragma unroll
        for (int m = 0; m < 4; ++m)
          acc[m][i] = __builtin_amdgcn_mfma_f32_16x16x32_bf16(am[m], bf[cur][i], acc[m][i], 0, 0, 0);
    }
  }

  // bias1 + ReLU + bf16 into regs; overlay h1 into feats after barrier
  uint32_t h1r[2][8];
  #pragma unroll
  for (int i = 0; i < 2; ++i) {
    float bias = b1[(w * 2 + i) * 16 + lr];
    #pragma unroll
    for (int m = 0; m < 4; ++m) {
      float v0 = fmaxf(acc[m][i][0] + bias, 0.f);
      float v1 = fmaxf(acc[m][i][1] + bias, 0.f);
      float v2 = fmaxf(acc[m][i][2] + bias, 0.f);
      float v3 = fmaxf(acc[m][i][3] + bias, 0.f);
      h1r[i][m * 2]     = pk2(v0, v1);
      h1r[i][m * 2 + 1] = pk2(v2, v3);
    }
  }
  __syncthreads();   // pass-B buffer fully consumed

  ushort* h1 = feats;   // flat overlay [row*H1S + col]
  #pragma unroll
  for (int i = 0; i < 2; ++i) {
    int col = (w * 2 + i) * 16 + lr;
    #pragma unroll
    for (int m = 0; m < 4; ++m) {
      int row0 = m * 16 + lk * 4;
      h1[(row0)     * H1S + col] = (ushort)(h1r[i][m * 2]);
      h1[(row0 + 1) * H1S + col] = (ushort)(h1r[i][m * 2] >> 16);
      h1[(row0 + 2) * H1S + col] = (ushort)(h1r[i][m * 2 + 1]);
      h1[(row0 + 3) * H1S + col] = (ushort)(h1r[i][m * 2 + 1] >> 16);
    }
  }
  __syncthreads();

  // ---- GEMM2: h1[64x256] @ W2[256x128]; wave w owns n-tile w ----
  f32x4 acc2[4];
  #pragma unroll
  for (int m = 0; m < 4; ++m) acc2[m] = (f32x4){0.f, 0.f, 0.f, 0.f};

  const ushort* aB2 = h1 + lr * H1S + lk * 8;
  const ushort* bW2 = w2p + (size_t)w * KS2 * 512 + l * 8;

  short8v b2f[2];
  b2f[0] = *(const short8v*)(bW2);

  #pragma unroll
  for (int ks = 0; ks < KS2; ++ks) {
    int cur = ks & 1, nxt = cur ^ 1;
    if (ks + 1 < KS2)
      b2f[nxt] = *(const short8v*)(bW2 + (size_t)(ks + 1) * 512);
    #pragma unroll
    for (int m = 0; m < 4; ++m) {
      short8v am = *(const short8v*)(aB2 + m * 16 * H1S + ks * 32);
      acc2[m] = __builtin_amdgcn_mfma_f32_16x16x32_bf16(am, b2f[cur], acc2[m], 0, 0, 0);
    }
  }

  // ---- GEMM3 in-register: lane col = w*16+lr; shfl-reduce then LDS atomicAdd ----
  {
    int col = w * 16 + lr;
    float bias = b2[col];
    float w3v = W3[col];
    #pragma unroll
    for (int m = 0; m < 4; ++m) {
      #pragma unroll
      for (int r = 0; r < 4; ++r) {
        float h = fmaxf(acc2[m][r] + bias, 0.f) * w3v;
        h += __shfl_xor(h, 1);
        h += __shfl_xor(h, 2);
        h += __shfl_xor(h, 4);
        h += __shfl_xor(h, 8);
        if (lr == 0) atomicAdd(&outacc[m * 16 + lk * 4 + r], h);
      }
    }
  }
  __syncthreads();

  if (tid < 64) out[pb + tid] = outacc[tid];
}

extern "C" void kernel_launch(void* const* d_in, const int* in_sizes, int n_in,
                              void* d_out, int out_size, void* d_ws, size_t ws_size,
                              hipStream_t stream) {
  const float* x     = (const float*)d_in[0];
  const int*   ei    = (const int*)d_in[1];
  const int*   pairs = (const int*)d_in[2];
  const float* W1    = (const float*)d_in[3];
  const float* b1    = (const float*)d_in[4];
  const float* W2    = (const float*)d_in[5];
  const float* b2    = (const float*)d_in[6];
  const float* W3    = (const float*)d_in[7];
  const float* b3    = (const float*)d_in[8];
  float* out = (float*)d_out;

  int N = in_sizes[0] / IN_CH;       // 8192
  int E = in_sizes[1] / 2;           // 262144
  int P = in_sizes[2] / 2;           // 65536
  int roww = (N + 31) >> 5;          // 256

  char* wsb = (char*)d_ws;
  uint32_t* bits   = (uint32_t*)wsb;                     size_t off = (size_t)N * roww * 4;
  float2* dn       = (float2*)(wsb + off);               off += (size_t)N * 8;
  float2* nodeinv  = (float2*)(wsb + off);               off += (size_t)N * 8;
  ushort* adjl     = (ushort*)(wsb + off);               off += (size_t)N * CAP * 2;
  ushort* xbf      = (ushort*)(wsb + off);               off += (size_t)N * IN_CH * 2;
  ushort* w1pack   = (ushort*)(wsb + off);               off += (size_t)T1PACK * 8 * 2;
  ushort* w2pack   = (ushort*)(wsb + off);               off += (size_t)T2PACK * 8 * 2;

  int nwords = N * roww;
  k_prep<<<1024, 256, 0, stream>>>(W1, W2, w1pack, w2pack, bits, nwords);
  k_build_adj<<<(E + 255) / 256, 256, 0, stream>>>(ei, E, roww, bits);
  k_node_lists<<<(N + 3) / 4, 256, 0, stream>>>(bits, x, N, roww, dn, nodeinv, adjl, xbf);
  k_mlp11<<<P / 64, 512, 0, stream>>>(xbf, pairs, bits, roww, dn, nodeinv, adjl,
                                      w1pack, b1, w2pack, b2, W3, b3, out, P);
}

// Round 13
// 74.024 us; speedup vs baseline: 1.0816x; 1.0816x over previous
//
#include <hip/hip_runtime.h>
#include <hip/hip_bf16.h>

#define IN_CH   128
#define HIDDEN  256
#define H2DIM   128
#define KS1     17             // GEMM1 k-steps total (K=544); pass A: 0..7, pass B: 8..16
#define KS2     8              // GEMM2 k-steps (K=256)
#define NT1     16
#define NT2     8
#define FSTR    296            // feats LDS k-stride (ushort) for the half buffer
#define H1S     264            // h1 overlay stride (ushort)
#define CAP     64             // adjacency-list cap (fallbacks if deg>CAP)
#define T1PACK  (NT1*KS1*64)   // 17408
#define T2PACK  (NT2*KS2*64)   // 4096

typedef short short8v __attribute__((ext_vector_type(8)));
typedef float f32x4   __attribute__((ext_vector_type(4)));

__device__ __forceinline__ ushort f2bf(float f) {
  union { float f; uint32_t u; } c; c.f = f;
  uint32_t u = c.u + 0x7FFFu + ((c.u >> 16) & 1u);   // RNE
  return (ushort)(u >> 16);
}
__device__ __forceinline__ float bf2f(ushort h) {
  union { uint32_t u; float f; } c; c.u = ((uint32_t)h) << 16;
  return c.f;
}
__device__ __forceinline__ float bfLo(uint32_t u) { return bf2f((ushort)(u & 0xffffu)); }
__device__ __forceinline__ float bfHi(uint32_t u) { return bf2f((ushort)(u >> 16)); }
__device__ __forceinline__ uint32_t pk2(float a, float b) {
  __hip_bfloat162 h = __float22bfloat162_rn(make_float2(a, b));
  union { __hip_bfloat162 h; uint32_t u; } c; c.h = h;
  return c.u;
}

// ---------------- kernel 1: zero bitset + pack W1(K-folded)/W2 ----------------
__global__ void k_prep(const float* __restrict__ W1, const float* __restrict__ W2,
                       ushort* __restrict__ w1p, ushort* __restrict__ w2p,
                       uint32_t* __restrict__ bits, int nwords) {
  int t = blockIdx.x * blockDim.x + threadIdx.x;
  if (t < T1PACK) {
    int l = t & 63;
    int rest = t >> 6;
    int ks = rest % KS1;
    int nt = rest / KS1;
    int n  = nt * 16 + (l & 15);
    int k0 = ks * 32 + (l >> 4) * 8;
    short8v v;
    #pragma unroll
    for (int j = 0; j < 8; ++j) {
      int k = k0 + j;
      float val;
      if (k < 128)      val = W1[(size_t)k * HIDDEN + n] + W1[(size_t)(512 + k) * HIDDEN + n];
      else if (k < 256) val = W1[(size_t)k * HIDDEN + n] + W1[(size_t)(384 + k) * HIDDEN + n];
      else if (k < 512) val = W1[(size_t)k * HIDDEN + n];
      else if (k < 516) val = W1[(size_t)(k + 128) * HIDDEN + n];   // rows 640..643
      else              val = 0.f;
      v[j] = (short)f2bf(val);
    }
    *(short8v*)(w1p + (size_t)t * 8) = v;
  } else if (t < T1PACK + T2PACK) {
    int t2 = t - T1PACK;
    int l = t2 & 63;
    int rest = t2 >> 6;
    int ks = rest % KS2;
    int nt = rest / KS2;
    int n  = nt * 16 + (l & 15);
    int k0 = ks * 32 + (l >> 4) * 8;
    short8v v;
    #pragma unroll
    for (int j = 0; j < 8; ++j)
      v[j] = (short)f2bf(W2[(size_t)(k0 + j) * H2DIM + n]);
    *(short8v*)(w2p + (size_t)t2 * 8) = v;
  }
  int stride = gridDim.x * blockDim.x;
  for (int i = t; i < nwords; i += stride) bits[i] = 0u;
}

// ---------------- kernel 2: build adjacency bitset ----------------
__global__ void k_build_adj(const int* __restrict__ ei, int E, int roww,
                            uint32_t* __restrict__ bits) {
  int e = blockIdx.x * blockDim.x + threadIdx.x;
  if (e >= E) return;
  int u = ei[e];
  int v = ei[E + e];
  if (u == v) return;
  atomicOr((unsigned int*)&bits[(size_t)u * roww + (v >> 5)], 1u << (v & 31));
}

// -- kernel 3: node stats (packed float2) + sorted adjacency lists + bf16 x --
__global__ void k_node_lists(const uint32_t* __restrict__ bits, const float* __restrict__ x,
                             int nnodes, int roww,
                             float2* __restrict__ dn, float2* __restrict__ nodeinv,
                             ushort* __restrict__ adjl, ushort* __restrict__ xbf) {
  int node = blockIdx.x * (blockDim.x >> 6) + (threadIdx.x >> 6);
  int lane = threadIdx.x & 63;
  if (node >= nnodes) return;
  const uint32_t* row = bits + (size_t)node * roww;
  uint32_t wd[4];
  int c = 0;
  #pragma unroll
  for (int j = 0; j < 4; ++j) { wd[j] = row[lane * 4 + j]; c += __popc(wd[j]); }
  int sum = c;
  #pragma unroll
  for (int off = 1; off < 64; off <<= 1) {
    int t = __shfl_up(sum, off);
    if (lane >= off) sum += t;
  }
  int excl = sum - c;
  int total = __shfl(sum, 63);
  ushort* lst = adjl + (size_t)node * CAP;
  int pos = excl;
  #pragma unroll
  for (int j = 0; j < 4; ++j) {
    uint32_t m = wd[j];
    int base = (lane * 4 + j) * 32;
    while (m) {
      int b = __ffs(m) - 1;
      if (pos < CAP) lst[pos] = (ushort)(base + b);
      ++pos;
      m &= m - 1;
    }
  }
  float2 xa = *(const float2*)(x + (size_t)node * IN_CH + 2 * lane);
  *(uint32_t*)(xbf + (size_t)node * IN_CH + 2 * lane) = pk2(xa.x, xa.y);
  float ss = xa.x * xa.x + xa.y * xa.y;
  #pragma unroll
  for (int off = 32; off; off >>= 1) ss += __shfl_xor(ss, off);
  if (lane == 0) {
    float d = (float)total;
    dn[node] = make_float2(d, sqrtf(ss));
    float il = (total > 1) ? 1.0f / logf(d) : 0.0f;
    float ig = (total > 0) ? 1.0f / d : 0.0f;
    nodeinv[node] = make_float2(il, ig);
  }
}

// ---------------- kernel 4: fused features + pair stats + MFMA MLP ----------
// 64 pairs/block, 512 threads (8 waves). R11 structure (best measured): bf16
// x-gathers, bitset probe stats; plus direct global pair loads (no LDS staging,
// one fewer barrier) and early GEMM1 B-fragment prefetch.
__global__ __launch_bounds__(512, 4) void k_mlp12(
    const ushort* __restrict__ xbf, const int* __restrict__ pairs,
    const uint32_t* __restrict__ bits, int roww,
    const float2* __restrict__ dn, const float2* __restrict__ nodeinv,
    const ushort* __restrict__ adjl,
    const ushort* __restrict__ w1p, const float* __restrict__ b1,
    const ushort* __restrict__ w2p, const float* __restrict__ b2,
    const float* __restrict__ W3, const float* __restrict__ b3,
    float* __restrict__ out, int P)
{
  __shared__ ushort feats[64 * FSTR];   // 37,888 B; h1 (stride 264) overlays later
  __shared__ float outacc[64];

  int tid = threadIdx.x;
  int pb = blockIdx.x * 64;
  int w  = tid >> 6, l = tid & 63;
  int pg = l >> 3, g = l & 7;        // feature build: 8 lanes per pair
  int lr = l & 15;                   // MFMA A row / B,C col within tile
  int lk = l >> 4;                   // MFMA k-group / C row group

  if (tid < 64) outacc[tid] = b3[0];

  // direct pair load (no LDS staging, no entry barrier)
  int p = w * 8 + pg;
  int2 pr = ((const int2*)pairs)[pb + p];
  int u = pr.x, v = pr.y;
  ushort* fpR = feats + p * FSTR;
  ushort* fp  = fpR + g * 16;

  // early GEMM1 pass-A B prefetch: address known at entry; completes under
  // the feature/stats phase.
  const ushort* bW = w1p + (size_t)(w * 2) * KS1 * 512 + l * 8;
  short8v bpre0 = *(const short8v*)(bW);
  short8v bpre1 = *(const short8v*)(bW + (size_t)KS1 * 512);

  // ---- pass A build: bf16 xu -> cols [0,128), xv -> [128,256); cos; pad ----
  {
    const ushort* xup = xbf + (size_t)u * IN_CH + g * 16;
    const ushort* xvp = xbf + (size_t)v * IN_CH + g * 16;
    uint4 A0 = *(const uint4*)(xup);
    uint4 A1 = *(const uint4*)(xup + 8);
    uint4 B0 = *(const uint4*)(xvp);
    uint4 B1 = *(const uint4*)(xvp + 8);
    *(uint4*)(fp)       = A0;
    *(uint4*)(fp + 8)   = A1;
    *(uint4*)(fp + 128) = B0;
    *(uint4*)(fp + 136) = B1;
    float suv = bfLo(A0.x)*bfLo(B0.x) + bfHi(A0.x)*bfHi(B0.x)
              + bfLo(A0.y)*bfLo(B0.y) + bfHi(A0.y)*bfHi(B0.y)
              + bfLo(A0.z)*bfLo(B0.z) + bfHi(A0.z)*bfHi(B0.z)
              + bfLo(A0.w)*bfLo(B0.w) + bfHi(A0.w)*bfHi(B0.w)
              + bfLo(A1.x)*bfLo(B1.x) + bfHi(A1.x)*bfHi(B1.x)
              + bfLo(A1.y)*bfLo(B1.y) + bfHi(A1.y)*bfHi(B1.y)
              + bfLo(A1.z)*bfLo(B1.z) + bfHi(A1.z)*bfHi(B1.z)
              + bfLo(A1.w)*bfLo(B1.w) + bfHi(A1.w)*bfHi(B1.w);
    suv += __shfl_xor(suv, 1);
    suv += __shfl_xor(suv, 2);
    suv += __shfl_xor(suv, 4);
    if (g == 0) {
      fpR[256] = f2bf(suv / fmaxf(dn[u].y * dn[v].y, 1e-8f));
    }
    if (g < 7) *(uint2*)(fpR + 260 + 4 * g) = make_uint2(0u, 0u);
  }

  // ---- pair stats: batched probes (deg->adjl->bits), ballot reduce ----
  {
    int sdmin[8], snbs[8];
    uint32_t swrd[8];
    bool sfall = false;
    #pragma unroll
    for (int pp = 0; pp < 8; ++pp) {
      int2 pq = ((const int2*)pairs)[pb + w * 8 + pp];
      int uu = pq.x, vv = pq.y;
      int du = (int)dn[uu].x, dv = (int)dn[vv].x;
      int nu = adjl[(size_t)uu * CAP + l];
      int nv = adjl[(size_t)vv * CAP + l];
      bool ule = du <= dv;
      sdmin[pp] = ule ? du : dv;
      int o  = ule ? vv : uu;
      int nb = (ule ? nu : nv) & 8191;
      snbs[pp] = nb;
      swrd[pp] = bits[(size_t)o * roww + (nb >> 5)];
      sfall |= (sdmin[pp] > CAP);
    }
    if (!sfall) {
      #pragma unroll
      for (int pp = 0; pp < 8; ++pp) {
        bool h = (l < sdmin[pp]) && ((swrd[pp] >> (snbs[pp] & 31)) & 1u);
        unsigned long long mask = __ballot(h);
        float cnv = (float)__popcll(mask);
        float aa = 0.f, ra = 0.f;
        if (mask) {
          float il = 0.f, ig = 0.f;
          if (h) { float2 nv2 = nodeinv[snbs[pp]]; il = nv2.x; ig = nv2.y; }
          while (mask) {
            int ln = __ffsll(mask) - 1;
            aa += __shfl(il, ln);
            ra += __shfl(ig, ln);
            mask &= mask - 1;
          }
        }
        if (l == 0) {
          ushort* fq = feats + (w * 8 + pp) * FSTR;
          fq[257] = f2bf(cnv); fq[258] = f2bf(aa); fq[259] = f2bf(ra);
        }
      }
    } else {
      for (int pp = 0; pp < 8; ++pp) {
        int2 pq = ((const int2*)pairs)[pb + w * 8 + pp];
        int uu = pq.x, vv = pq.y;
        float cnL = 0.f, aaL = 0.f, raL = 0.f;
        const uint32_t* ru = bits + (size_t)uu * roww;
        const uint32_t* rv = bits + (size_t)vv * roww;
        for (int wd = l; wd < roww; wd += 64) {
          uint32_t c = ru[wd] & rv[wd];
          cnL += (float)__popc(c);
          while (c) {
            int bb = __ffs(c) - 1;
            int idx = wd * 32 + bb;
            float2 nv2 = nodeinv[idx];
            aaL += nv2.x; raL += nv2.y;
            c &= c - 1;
          }
        }
        #pragma unroll
        for (int off = 32; off; off >>= 1) {
          cnL += __shfl_xor(cnL, off);
          aaL += __shfl_xor(aaL, off);
          raL += __shfl_xor(raL, off);
        }
        if (l == 0) {
          ushort* fq = feats + (w * 8 + pp) * FSTR;
          fq[257] = f2bf(cnL); fq[258] = f2bf(aaL); fq[259] = f2bf(raL);
        }
      }
    }
  }
  __syncthreads();

  // ---- GEMM1 accumulators persist across both k-passes ----
  f32x4 acc[4][2];
  #pragma unroll
  for (int m = 0; m < 4; ++m)
    #pragma unroll
    for (int i = 0; i < 2; ++i) acc[m][i] = (f32x4){0.f, 0.f, 0.f, 0.f};

  const ushort* aB = feats + lr * FSTR + lk * 8;

  // ---- GEMM1 pass A: ks 0..7 (k 0..255) ----
  {
    short8v bf[2][2];
    bf[0][0] = bpre0;
    bf[0][1] = bpre1;
    #pragma unroll
    for (int ks = 0; ks < 8; ++ks) {
      int cur = ks & 1, nxt = cur ^ 1;
      if (ks + 1 < 8) {
        #pragma unroll
        for (int i = 0; i < 2; ++i)
          bf[nxt][i] = *(const short8v*)(bW + (size_t)(i * KS1 + ks + 1) * 512);
      }
      short8v am[4];
      #pragma unroll
      for (int m = 0; m < 4; ++m)
        am[m] = *(const short8v*)(aB + m * 16 * FSTR + ks * 32);
      #pragma unroll
      for (int i = 0; i < 2; ++i)
        #pragma unroll
        for (int m = 0; m < 4; ++m)
          acc[m][i] = __builtin_amdgcn_mfma_f32_16x16x32_bf16(am[m], bf[cur][i], acc[m][i], 0, 0, 0);
    }
  }
  __syncthreads();   // all waves done reading pass-A cols

  // ---- pass B build: read bf16 xu/xv back from LDS; prod -> [0,128),
  //      absdiff -> [128,256). Same-thread same-cells: no cross-thread hazard.
  {
    uint4 A0 = *(uint4*)(fp);
    uint4 A1 = *(uint4*)(fp + 8);
    uint4 B0 = *(uint4*)(fp + 128);
    uint4 B1 = *(uint4*)(fp + 136);
    uint4 P0, P1, D0, D1;
    #define PD(Au, Bu, Pu, Du)                                                 \
      {                                                                        \
        float alo = bfLo(Au), ahi = bfHi(Au);                                  \
        float blo = bfLo(Bu), bhi = bfHi(Bu);                                  \
        Pu = pk2(alo * blo, ahi * bhi);                                        \
        Du = pk2(fabsf(alo - blo), fabsf(ahi - bhi));                          \
      }
    PD(A0.x, B0.x, P0.x, D0.x) PD(A0.y, B0.y, P0.y, D0.y)
    PD(A0.z, B0.z, P0.z, D0.z) PD(A0.w, B0.w, P0.w, D0.w)
    PD(A1.x, B1.x, P1.x, D1.x) PD(A1.y, B1.y, P1.y, D1.y)
    PD(A1.z, B1.z, P1.z, D1.z) PD(A1.w, B1.w, P1.w, D1.w)
    #undef PD
    *(uint4*)(fp)       = P0;
    *(uint4*)(fp + 8)   = P1;
    *(uint4*)(fp + 128) = D0;
    *(uint4*)(fp + 136) = D1;
  }
  __syncthreads();

  // ---- GEMM1 pass B: ks 8..16 (k 256..543; buffer col = (ks-8)*32) ----
  {
    short8v bf[2][2];
    #pragma unroll
    for (int i = 0; i < 2; ++i)
      bf[0][i] = *(const short8v*)(bW + (size_t)(i * KS1 + 8) * 512);
    #pragma unroll
    for (int ks = 8; ks < KS1; ++ks) {
      int cur = ks & 1, nxt = cur ^ 1;
      if (ks + 1 < KS1) {
        #pragma unroll
        for (int i = 0; i < 2; ++i)
          bf[nxt][i] = *(const short8v*)(bW + (size_t)(i * KS1 + ks + 1) * 512);
      }
      short8v am[4];
      #pragma unroll
      for (int m = 0; m < 4; ++m)
        am[m] = *(const short8v*)(aB + m * 16 * FSTR + (ks - 8) * 32);
      #pragma unroll
      for (int i = 0; i < 2; ++i)
        #pragma unroll
        for (int m = 0; m < 4; ++m)
          acc[m][i] = __builtin_amdgcn_mfma_f32_16x16x32_bf16(am[m], bf[cur][i], acc[m][i], 0, 0, 0);
    }
  }

  // bias1 + ReLU + bf16 into regs; overlay h1 into feats after barrier
  uint32_t h1r[2][8];
  #pragma unroll
  for (int i = 0; i < 2; ++i) {
    float bias = b1[(w * 2 + i) * 16 + lr];
    #pragma unroll
    for (int m = 0; m < 4; ++m) {
      float v0 = fmaxf(acc[m][i][0] + bias, 0.f);
      float v1 = fmaxf(acc[m][i][1] + bias, 0.f);
      float v2 = fmaxf(acc[m][i][2] + bias, 0.f);
      float v3 = fmaxf(acc[m][i][3] + bias, 0.f);
      h1r[i][m * 2]     = pk2(v0, v1);
      h1r[i][m * 2 + 1] = pk2(v2, v3);
    }
  }
  __syncthreads();   // pass-B buffer fully consumed

  ushort* h1 = feats;   // flat overlay [row*H1S + col]
  #pragma unroll
  for (int i = 0; i < 2; ++i) {
    int col = (w * 2 + i) * 16 + lr;
    #pragma unroll
    for (int m = 0; m < 4; ++m) {
      int row0 = m * 16 + lk * 4;
      h1[(row0)     * H1S + col] = (ushort)(h1r[i][m * 2]);
      h1[(row0 + 1) * H1S + col] = (ushort)(h1r[i][m * 2] >> 16);
      h1[(row0 + 2) * H1S + col] = (ushort)(h1r[i][m * 2 + 1]);
      h1[(row0 + 3) * H1S + col] = (ushort)(h1r[i][m * 2 + 1] >> 16);
    }
  }
  __syncthreads();

  // ---- GEMM2: h1[64x256] @ W2[256x128]; wave w owns n-tile w ----
  f32x4 acc2[4];
  #pragma unroll
  for (int m = 0; m < 4; ++m) acc2[m] = (f32x4){0.f, 0.f, 0.f, 0.f};

  const ushort* aB2 = h1 + lr * H1S + lk * 8;
  const ushort* bW2 = w2p + (size_t)w * KS2 * 512 + l * 8;

  short8v b2f[2];
  b2f[0] = *(const short8v*)(bW2);

  #pragma unroll
  for (int ks = 0; ks < KS2; ++ks) {
    int cur = ks & 1, nxt = cur ^ 1;
    if (ks + 1 < KS2)
      b2f[nxt] = *(const short8v*)(bW2 + (size_t)(ks + 1) * 512);
    #pragma unroll
    for (int m = 0; m < 4; ++m) {
      short8v am = *(const short8v*)(aB2 + m * 16 * H1S + ks * 32);
      acc2[m] = __builtin_amdgcn_mfma_f32_16x16x32_bf16(am, b2f[cur], acc2[m], 0, 0, 0);
    }
  }

  // ---- GEMM3 in-register: lane col = w*16+lr; shfl-reduce then LDS atomicAdd ----
  {
    int col = w * 16 + lr;
    float bias = b2[col];
    float w3v = W3[col];
    #pragma unroll
    for (int m = 0; m < 4; ++m) {
      #pragma unroll
      for (int r = 0; r < 4; ++r) {
        float h = fmaxf(acc2[m][r] + bias, 0.f) * w3v;
        h += __shfl_xor(h, 1);
        h += __shfl_xor(h, 2);
        h += __shfl_xor(h, 4);
        h += __shfl_xor(h, 8);
        if (lr == 0) atomicAdd(&outacc[m * 16 + lk * 4 + r], h);
      }
    }
  }
  __syncthreads();

  if (tid < 64) out[pb + tid] = outacc[tid];
}

extern "C" void kernel_launch(void* const* d_in, const int* in_sizes, int n_in,
                              void* d_out, int out_size, void* d_ws, size_t ws_size,
                              hipStream_t stream) {
  const float* x     = (const float*)d_in[0];
  const int*   ei    = (const int*)d_in[1];
  const int*   pairs = (const int*)d_in[2];
  const float* W1    = (const float*)d_in[3];
  const float* b1    = (const float*)d_in[4];
  const float* W2    = (const float*)d_in[5];
  const float* b2    = (const float*)d_in[6];
  const float* W3    = (const float*)d_in[7];
  const float* b3    = (const float*)d_in[8];
  float* out = (float*)d_out;

  int N = in_sizes[0] / IN_CH;       // 8192
  int E = in_sizes[1] / 2;           // 262144
  int P = in_sizes[2] / 2;           // 65536
  int roww = (N + 31) >> 5;          // 256

  char* wsb = (char*)d_ws;
  uint32_t* bits   = (uint32_t*)wsb;                     size_t off = (size_t)N * roww * 4;
  float2* dn       = (float2*)(wsb + off);               off += (size_t)N * 8;
  float2* nodeinv  = (float2*)(wsb + off);               off += (size_t)N * 8;
  ushort* adjl     = (ushort*)(wsb + off);               off += (size_t)N * CAP * 2;
  ushort* xbf      = (ushort*)(wsb + off);               off += (size_t)N * IN_CH * 2;
  ushort* w1pack   = (ushort*)(wsb + off);               off += (size_t)T1PACK * 8 * 2;
  ushort* w2pack   = (ushort*)(wsb + off);               off += (size_t)T2PACK * 8 * 2;

  int nwords = N * roww;
  k_prep<<<1024, 256, 0, stream>>>(W1, W2, w1pack, w2pack, bits, nwords);
  k_build_adj<<<(E + 255) / 256, 256, 0, stream>>>(ei, E, roww, bits);
  k_node_lists<<<(N + 3) / 4, 256, 0, stream>>>(bits, x, N, roww, dn, nodeinv, adjl, xbf);
  k_mlp12<<<P / 64, 512, 0, stream>>>(xbf, pairs, bits, roww, dn, nodeinv, adjl,
                                      w1pack, b1, w2pack, b2, W3, b3, out, P);
}